// Round 18
// baseline (123.501 us; speedup 1.0000x reference)
//
#include <hip/hip_runtime.h>
#include <cstdint>
#include <cstddef>

#define S_LEN 2048
#define DIN   512
#define DOUT  64
#define NB    4
#define NH    8

typedef __attribute__((ext_vector_type(8))) short bf16x8;
typedef __attribute__((ext_vector_type(8))) _Float16 f16x8;
typedef __attribute__((ext_vector_type(4))) float f32x4;
typedef __attribute__((ext_vector_type(16))) float f32x16;

static __device__ __forceinline__ f32x4 mfma16(bf16x8 a, bf16x8 b, f32x4 c) {
    return __builtin_amdgcn_mfma_f32_16x16x32_bf16(a, b, c, 0, 0, 0);
}
static __device__ __forceinline__ f32x16 mfma32h(f16x8 a, f16x8 b, f32x16 c) {
    return __builtin_amdgcn_mfma_f32_32x32x16_f16(a, b, c, 0, 0, 0);
}

static __device__ __forceinline__ uint16_t f2bf(float x) {
    uint32_t u = __builtin_bit_cast(uint32_t, x);
    u += 0x7fffu + ((u >> 16) & 1u);
    return (uint16_t)(u >> 16);
}
static __device__ __forceinline__ float bf2f(uint16_t h) {
    uint32_t u = ((uint32_t)h) << 16;
    return __builtin_bit_cast(float, u);
}
static __device__ __forceinline__ uint32_t cvt_pk_bf16(float lo, float hi) {
    uint32_t r;
    asm("v_cvt_pk_bf16_f32 %0, %1, %2" : "=v"(r) : "v"(lo), "v"(hi));
    return r;
}
static __device__ __forceinline__ uint32_t cvt_pkrtz_f16(float lo, float hi) {
    return __builtin_bit_cast(uint32_t, __builtin_amdgcn_cvt_pkrtz(lo, hi));
}

// ---------------------------------------------------------------------------
// Kernel 1: weight prep via LDS transpose (coalesced both sides).
// ---------------------------------------------------------------------------
__global__ __launch_bounds__(256) void prep_w(
    const float* __restrict__ w, const float* __restrict__ wo,
    uint16_t* __restrict__ whiT, uint16_t* __restrict__ wloT,
    uint16_t* __restrict__ woT)
{
    __shared__ float tile[64][65];
    const int blk = blockIdx.x;
    const int t = threadIdx.x;
    const int tq = t >> 6, tr = t & 63;

    if (blk < 192) {
        const int hp = blk >> 3, i0 = (blk & 7) * 64;
        const int p = hp % 3;
        const float s = (p == 0) ? 0.18033688011112042f : 1.0f; // 0.125*log2(e)
        const float* __restrict__ src = w + (size_t)hp * (DIN * DOUT);
        #pragma unroll
        for (int r = 0; r < 16; ++r) {
            const int ir = r * 4 + tq;
            tile[ir][tr] = src[(size_t)(i0 + ir) * DOUT + tr];
        }
        __syncthreads();
        uint16_t* __restrict__ dh = whiT + (size_t)hp * (DOUT * DIN);
        uint16_t* __restrict__ dl = wloT + (size_t)hp * (DOUT * DIN);
        #pragma unroll
        for (int r = 0; r < 16; ++r) {
            const int o = r * 4 + tq;
            const float v = tile[tr][o] * s;
            const uint16_t hi = f2bf(v);
            dh[(size_t)o * DIN + i0 + tr] = hi;
            dl[(size_t)o * DIN + i0 + tr] = f2bf(v - bf2f(hi));
        }
    } else {
        const int i0 = (blk - 192) * 64;
        #pragma unroll
        for (int r = 0; r < 16; ++r) {
            const int ir = r * 4 + tq;
            tile[ir][tr] = wo[(size_t)(i0 + ir) * DOUT + tr];
        }
        __syncthreads();
        #pragma unroll
        for (int r = 0; r < 16; ++r) {
            const int o = r * 4 + tq;
            woT[(size_t)o * DIN + i0 + tr] = f2bf(tile[tr][o]);
        }
    }
}

// ---------------------------------------------------------------------------
// Kernel 2: split x [8192][512] fp32 -> xhi/xlo bf16 (vectorized, one pass).
// ---------------------------------------------------------------------------
__global__ __launch_bounds__(256) void split_x(
    const float* __restrict__ x, uint16_t* __restrict__ xhi, uint16_t* __restrict__ xlo)
{
    const size_t idx = ((size_t)blockIdx.x * 256 + threadIdx.x) * 8;
    const float4 a = *(const float4*)(x + idx);
    const float4 b = *(const float4*)(x + idx + 4);
    const float xv[8] = {a.x, a.y, a.z, a.w, b.x, b.y, b.z, b.w};
    union { uint16_t u[8]; uint4 v; } H, L;
    #pragma unroll
    for (int j = 0; j < 8; ++j) {
        const uint16_t hi = f2bf(xv[j]);
        H.u[j] = hi;
        L.u[j] = f2bf(xv[j] - bf2f(hi));
    }
    *(uint4*)(xhi + idx) = H.v;
    *(uint4*)(xlo + idx) = L.v;
}

// ---------------------------------------------------------------------------
// Kernel 3: QKV projection GEMM (fused 3-term, reg-staged; R15/R17 body).
// Outputs: q fp16 [bh][s][64]; K,V fragment-major tiles.
// ---------------------------------------------------------------------------
__global__ __launch_bounds__(256, 2) void gemm_qkv(
    const uint16_t* __restrict__ xhi, const uint16_t* __restrict__ xlo,
    const uint16_t* __restrict__ whiT, const uint16_t* __restrict__ wloT,
    uint16_t* __restrict__ qf, uint16_t* __restrict__ kfm,
    uint16_t* __restrict__ vfm)
{
    __shared__ __align__(16) uint16_t lds[4 * 128 * 64];   // 64 KB: ah|al|bh|bl

    const int bid = blockIdx.x;
    const int xcd = bid & 7, wi = bid >> 3;
    const int mt = xcd * 8 + wi / 12, nt = wi % 12;
    const int m0 = mt * 128, n0 = nt * 128;
    const int tid = threadIdx.x;
    const int l = tid & 63, w = tid >> 6;
    const int g = l >> 4, lm = l & 15;
    const int wm = w >> 1, wn = w & 1;

    const f32x4 Z = {0.f, 0.f, 0.f, 0.f};
    f32x4 acc[4][4];
    #pragma unroll
    for (int a = 0; a < 4; ++a)
        #pragma unroll
        for (int b = 0; b < 4; ++b) acc[a][b] = Z;

    int srow[4], scol[4];
    #pragma unroll
    for (int i = 0; i < 4; ++i) {
        const int c = i * 256 + tid;
        srow[i] = c >> 3;
        scol[i] = ((c & 7) * 8) ^ ((srow[i] & 7) << 3);
    }

    for (int kt = 0; kt < 8; ++kt) {
        const int k0 = kt * 64;
        uint4 stg[16];
        #pragma unroll
        for (int i = 0; i < 4; ++i) {
            const size_t aoff = (size_t)(m0 + srow[i]) * DIN + k0 + scol[i];
            const size_t boff = (size_t)(n0 + srow[i]) * DIN + k0 + scol[i];
            stg[i * 4 + 0] = *(const uint4*)(xhi  + aoff);
            stg[i * 4 + 1] = *(const uint4*)(xlo  + aoff);
            stg[i * 4 + 2] = *(const uint4*)(whiT + boff);
            stg[i * 4 + 3] = *(const uint4*)(wloT + boff);
        }
        #pragma unroll
        for (int i = 0; i < 4; ++i) {
            const int c8 = (i * 256 + tid) * 8;
            *(uint4*)&lds[c8]                 = stg[i * 4 + 0];
            *(uint4*)&lds[128 * 64 + c8]      = stg[i * 4 + 1];
            *(uint4*)&lds[2 * 128 * 64 + c8]  = stg[i * 4 + 2];
            *(uint4*)&lds[3 * 128 * 64 + c8]  = stg[i * 4 + 3];
        }
        __syncthreads();

        bf16x8 ah[4][2], al[4][2];
        #pragma unroll
        for (int mi = 0; mi < 4; ++mi) {
            const int r = wm * 64 + mi * 16 + lm;
            const int rb = r * 128;
            #pragma unroll
            for (int kk = 0; kk < 2; ++kk) {
                const int cb = (kk * 64 + g * 16) ^ ((r & 7) << 4);
                ah[mi][kk] = *(const bf16x8*)((const char*)lds + rb + cb);
                al[mi][kk] = *(const bf16x8*)((const char*)lds + 16384 + rb + cb);
            }
        }
        #pragma unroll
        for (int ni = 0; ni < 4; ++ni) {
            const int r = wn * 64 + ni * 16 + lm;
            const int rb = r * 128;
            bf16x8 bh[2], bl[2];
            #pragma unroll
            for (int kk = 0; kk < 2; ++kk) {
                const int cb = (kk * 64 + g * 16) ^ ((r & 7) << 4);
                bh[kk] = *(const bf16x8*)((const char*)lds + 32768 + rb + cb);
                bl[kk] = *(const bf16x8*)((const char*)lds + 49152 + rb + cb);
            }
            #pragma unroll
            for (int mi = 0; mi < 4; ++mi) {
                acc[mi][ni] = mfma16(ah[mi][0], bh[0], acc[mi][ni]);
                acc[mi][ni] = mfma16(ah[mi][1], bh[1], acc[mi][ni]);
                acc[mi][ni] = mfma16(ah[mi][0], bl[0], acc[mi][ni]);
                acc[mi][ni] = mfma16(ah[mi][1], bl[1], acc[mi][ni]);
                acc[mi][ni] = mfma16(al[mi][0], bh[0], acc[mi][ni]);
                acc[mi][ni] = mfma16(al[mi][1], bh[1], acc[mi][ni]);
            }
        }
        __syncthreads();
    }

    #pragma unroll
    for (int ni = 0; ni < 4; ++ni) {
        const int n = n0 + wn * 64 + ni * 16 + lm;
        const int hp = n >> 6, o = n & 63;
        const int h = hp / 3, p = hp - h * 3;
        if (p == 0) {
            #pragma unroll
            for (int mi = 0; mi < 4; ++mi) {
                #pragma unroll
                for (int j = 0; j < 4; ++j) {
                    const int m = m0 + wm * 64 + mi * 16 + 4 * g + j;
                    const int b = m >> 11, s = m & 2047;
                    const size_t idx = ((size_t)(b * NH + h) * S_LEN + s) * DOUT + o;
                    const _Float16 hv = (_Float16)acc[mi][ni][j];  // RNE
                    qf[idx] = __builtin_bit_cast(uint16_t, hv);
                }
            }
        } else if (p == 1) {
            #pragma unroll
            for (int mi = 0; mi < 4; ++mi) {
                const int m = m0 + wm * 64 + mi * 16 + 4 * g;
                const int b = m >> 11, s = m & 2047;
                const int tile = s >> 6, sr = s & 63;
                const int gam = ((sr >> 5) * 4 + (o >> 4)) * 64 + ((o >> 3) & 1) * 32 + (sr & 31);
                uint16_t* __restrict__ dst =
                    kfm + ((size_t)((b * NH + h) * 32 + tile)) * 4096 + gam * 8 + (o & 7);
                #pragma unroll
                for (int j = 0; j < 4; ++j) {
                    const _Float16 hv = (_Float16)acc[mi][ni][j];
                    dst[j * 8] = __builtin_bit_cast(uint16_t, hv);  // granule+1 = +8 elem
                }
            }
        } else {
            #pragma unroll
            for (int mi = 0; mi < 4; ++mi) {
                const int m = m0 + wm * 64 + mi * 16 + 4 * g;
                const int b = m >> 11, s = m & 2047;
                const int tile = s >> 6, sc = s & 63;
                const int gam = ((o >> 5) * 4 + (sc >> 4)) * 64 + ((sc >> 3) & 1) * 32 + (o & 31);
                union { _Float16 h[4]; uint2 u; } pk;
                pk.h[0] = (_Float16)acc[mi][ni][0];
                pk.h[1] = (_Float16)acc[mi][ni][1];
                pk.h[2] = (_Float16)acc[mi][ni][2];
                pk.h[3] = (_Float16)acc[mi][ni][3];
                *(uint2*)(vfm + ((size_t)((b * NH + h) * 32 + tile)) * 4096
                              + gam * 8 + (sc & 7)) = pk.u;
            }
        }
    }
}

// ---------------------------------------------------------------------------
// Kernel 4: flash attention, KV-SPLIT x2: grid 1024 = 2 halves x 16 qt x
//   32 bh -> 4 blocks/CU = 4 waves/SIMD (2x R17). Each block does 16 KV
//   tiles of its half; writes NORMALIZED fp16 partial O/l + (m,l).
//   Body = R17 (fragment-major LDS dbuf, fp16 32x32 MFMA, in-register
//   softmax, linear reg-staging). Chain latency now hidden by TLP.
// ---------------------------------------------------------------------------
__global__ __launch_bounds__(256, 2) void attn_fwd(
    const uint16_t* __restrict__ qf, const uint16_t* __restrict__ kfm,
    const uint16_t* __restrict__ vfm,
    uint16_t* __restrict__ part0, uint16_t* __restrict__ part1,
    float2* __restrict__ ml)
{
    __shared__ __align__(16) char smem[32768];
    // kbuf0 @0, kbuf1 @8192, vbuf0 @16384, vbuf1 @24576
    char* __restrict__ vbufs = smem + 16384;

    const int bid = blockIdx.x;
    const int half = bid >> 9, qt = (bid >> 5) & 15, bh = bid & 31;
    const int tid = threadIdx.x;
    const int l = tid & 63, wq = tid >> 6;
    const int L = l >> 5, lq = l & 31;
    const size_t base = (size_t)bh * (S_LEN * DOUT);

    const uint16_t* __restrict__ ktb = kfm + (size_t)bh * 131072 + (size_t)half * 65536;
    const uint16_t* __restrict__ vtb = vfm + (size_t)bh * 131072 + (size_t)half * 65536;
    const uint32_t t16 = (uint32_t)tid * 16;

    const int qrow = qt * 128 + wq * 32 + lq;
    const uint16_t* qp = qf + base + (size_t)qrow * DOUT;
    f16x8 qv[4];
    #pragma unroll
    for (int dsub = 0; dsub < 4; ++dsub)
        qv[dsub] = *(const f16x8*)(qp + dsub * 16 + L * 8);

    f32x16 Zv;
    #pragma unroll
    for (int r = 0; r < 16; ++r) Zv[r] = 0.f;
    f32x16 Oa[2] = {Zv, Zv};
    float m_run = -INFINITY, l_run = 0.f;

    // named staging regs (2 sets x {K lo/hi half, V lo/hi half})
    uint4 kA0, kA1, vA0, vA1, kB0, kB1, vB0, vB1;

    auto qk_step = [&](const char* kb2, f32x16* dst) {
        __builtin_amdgcn_s_setprio(1);
        #pragma unroll
        for (int ks = 0; ks < 2; ++ks) {
            f32x16 s = Zv;
            #pragma unroll
            for (int dsub = 0; dsub < 4; ++dsub) {
                const uint32_t off = (uint32_t)(((ks * 4 + dsub) << 10) + (l << 4));
                const f16x8 kfr = *(const f16x8*)(kb2 + off);
                s = mfma32h(kfr, qv[dsub], s);
            }
            dst[ks] = s;
        }
        __builtin_amdgcn_s_setprio(0);
    };

    // prologue: tiles 0,1 loaded+committed; tiles 2,3 issued (in flight)
    kA0 = *(const uint4*)(ktb + (size_t)tid * 8);
    kA1 = *(const uint4*)(ktb + 2048 + (size_t)tid * 8);
    vA0 = *(const uint4*)(vtb + (size_t)tid * 8);
    vA1 = *(const uint4*)(vtb + 2048 + (size_t)tid * 8);
    kB0 = *(const uint4*)(ktb + 4096 + (size_t)tid * 8);
    kB1 = *(const uint4*)(ktb + 6144 + (size_t)tid * 8);
    vB0 = *(const uint4*)(vtb + 4096 + (size_t)tid * 8);
    vB1 = *(const uint4*)(vtb + 6144 + (size_t)tid * 8);
    *(uint4*)(smem + t16)          = kA0;
    *(uint4*)(smem + 4096 + t16)   = kA1;
    *(uint4*)(vbufs + t16)         = vA0;
    *(uint4*)(vbufs + 4096 + t16)  = vA1;
    *(uint4*)(smem + 8192 + t16)   = kB0;
    *(uint4*)(smem + 12288 + t16)  = kB1;
    *(uint4*)(vbufs + 8192 + t16)  = vB0;
    *(uint4*)(vbufs + 12288 + t16) = vB1;
    {
        const size_t o2 = (size_t)2 * 4096 + tid * 8, o3 = (size_t)3 * 4096 + tid * 8;
        kA0 = *(const uint4*)(ktb + o2); kA1 = *(const uint4*)(ktb + o2 + 2048);
        vA0 = *(const uint4*)(vtb + o2); vA1 = *(const uint4*)(vtb + o2 + 2048);
        kB0 = *(const uint4*)(ktb + o3); kB1 = *(const uint4*)(ktb + o3 + 2048);
        vB0 = *(const uint4*)(vtb + o3); vB1 = *(const uint4*)(vtb + o3 + 2048);
    }
    asm volatile("s_waitcnt lgkmcnt(0)" ::: "memory");
    __builtin_amdgcn_s_barrier();
    __builtin_amdgcn_sched_barrier(0);

    f32x16 saA[2], saB[2];
    qk_step(smem, saA);        // QK(0) from kbuf0

    auto iter = [&](int kt, f32x16* sa, f32x16* sb,
                    uint4& k0, uint4& k1, uint4& v0, uint4& v1) {
        // [a] QK(kt+1) MFMAs + V(kt) LDS prefetch
        qk_step(smem + ((kt + 1) & 1) * 8192, sb);
        const char* __restrict__ vb = vbufs + (kt & 1) * 8192;
        const uint32_t vo = (uint32_t)(l << 4);
        const f16x8 pv0 = *(const f16x8*)(vb + (0u << 10) + vo);
        const f16x8 pv1 = *(const f16x8*)(vb + (1u << 10) + vo);
        const f16x8 pv2 = *(const f16x8*)(vb + (2u << 10) + vo);
        const f16x8 pv3 = *(const f16x8*)(vb + (3u << 10) + vo);
        const f16x8 pv4 = *(const f16x8*)(vb + (4u << 10) + vo);
        const f16x8 pv5 = *(const f16x8*)(vb + (5u << 10) + vo);
        const f16x8 pv6 = *(const f16x8*)(vb + (6u << 10) + vo);
        const f16x8 pv7 = *(const f16x8*)(vb + (7u << 10) + vo);
        __builtin_amdgcn_sched_barrier(0);

        // [b] softmax(kt) on sa
        float mx[16];
        #pragma unroll
        for (int r = 0; r < 16; ++r) mx[r] = fmaxf(sa[0][r], sa[1][r]);
        #pragma unroll
        for (int st = 8; st >= 1; st >>= 1)
            #pragma unroll
            for (int r = 0; r < st; ++r) mx[r] = fmaxf(mx[r], mx[r + st]);
        float pmax = mx[0];
        pmax = fmaxf(pmax, __shfl_xor(pmax, 32));

        if (!__all(pmax - m_run <= 8.f)) {
            const float m_new = fmaxf(m_run, pmax);
            const float alpha = __builtin_amdgcn_exp2f(m_run - m_new);
            m_run = m_new;
            #pragma unroll
            for (int r = 0; r < 16; ++r) { Oa[0][r] *= alpha; Oa[1][r] *= alpha; }
            l_run *= alpha;
        }

        #pragma unroll
        for (int ks = 0; ks < 2; ++ks)
            #pragma unroll
            for (int r = 0; r < 16; ++r)
                sa[ks][r] = __builtin_amdgcn_exp2f(sa[ks][r] - m_run);

        float sm[16];
        #pragma unroll
        for (int r = 0; r < 16; ++r) sm[r] = sa[0][r] + sa[1][r];
        #pragma unroll
        for (int st = 8; st >= 1; st >>= 1)
            #pragma unroll
            for (int r = 0; r < st; ++r) sm[r] += sm[r + st];
        float lsum = sm[0];
        lsum += __shfl_xor(lsum, 32);
        l_run += lsum;

        // [c] pack P (fp16) into PV B-fragments; permlane VDST = lo pack
        f16x8 pfrag[4];
        #pragma unroll
        for (int ks = 0; ks < 2; ++ks) {
            uint32_t a0 = cvt_pkrtz_f16(sa[ks][0], sa[ks][1]);
            uint32_t a1 = cvt_pkrtz_f16(sa[ks][2], sa[ks][3]);
            uint32_t a2 = cvt_pkrtz_f16(sa[ks][4], sa[ks][5]);
            uint32_t a3 = cvt_pkrtz_f16(sa[ks][6], sa[ks][7]);
            asm volatile("v_permlane32_swap_b32 %0, %1" : "+v"(a0), "+v"(a2));
            asm volatile("v_permlane32_swap_b32 %0, %1" : "+v"(a1), "+v"(a3));
            union { uint32_t w[4]; f16x8 v; } u;
            u.w[0] = a0; u.w[1] = a1; u.w[2] = a2; u.w[3] = a3;
            pfrag[2 * ks] = u.v;
            uint32_t b0 = cvt_pkrtz_f16(sa[ks][8],  sa[ks][9]);
            uint32_t b1 = cvt_pkrtz_f16(sa[ks][10], sa[ks][11]);
            uint32_t b2 = cvt_pkrtz_f16(sa[ks][12], sa[ks][13]);
            uint32_t b3 = cvt_pkrtz_f16(sa[ks][14], sa[ks][15]);
            asm volatile("v_permlane32_swap_b32 %0, %1" : "+v"(b0), "+v"(b2));
            asm volatile("v_permlane32_swap_b32 %0, %1" : "+v"(b1), "+v"(b3));
            union { uint32_t w[4]; f16x8 v; } u2;
            u2.w[0] = b0; u2.w[1] = b1; u2.w[2] = b2; u2.w[3] = b3;
            pfrag[2 * ks + 1] = u2.v;
        }

        // [d] PV(kt)
        __builtin_amdgcn_s_setprio(1);
        Oa[0] = mfma32h(pv0, pfrag[0], Oa[0]);
        Oa[0] = mfma32h(pv1, pfrag[1], Oa[0]);
        Oa[0] = mfma32h(pv2, pfrag[2], Oa[0]);
        Oa[0] = mfma32h(pv3, pfrag[3], Oa[0]);
        Oa[1] = mfma32h(pv4, pfrag[0], Oa[1]);
        Oa[1] = mfma32h(pv5, pfrag[1], Oa[1]);
        Oa[1] = mfma32h(pv6, pfrag[2], Oa[1]);
        Oa[1] = mfma32h(pv7, pfrag[3], Oa[1]);
        __builtin_amdgcn_s_setprio(0);

        // [e] all waves done with buf[kt&1] -> commit tile kt+2, issue kt+4
        __builtin_amdgcn_s_barrier();
        {
            char* __restrict__ kb = smem + (kt & 1) * 8192;
            char* __restrict__ vbw = vbufs + (kt & 1) * 8192;
            *(uint4*)(kb + t16)         = k0;
            *(uint4*)(kb + 4096 + t16)  = k1;
            *(uint4*)(vbw + t16)        = v0;
            *(uint4*)(vbw + 4096 + t16) = v1;
            const int tk = (kt + 4 < 16) ? kt + 4 : 0;
            const size_t toff = (size_t)tk * 4096 + tid * 8;
            k0 = *(const uint4*)(ktb + toff);
            k1 = *(const uint4*)(ktb + toff + 2048);
            v0 = *(const uint4*)(vtb + toff);
            v1 = *(const uint4*)(vtb + toff + 2048);
        }
        asm volatile("s_waitcnt lgkmcnt(0)" ::: "memory");
        __builtin_amdgcn_sched_barrier(0);
        __builtin_amdgcn_s_barrier();
    };

    for (int t = 0; t < 8; ++t) {
        iter(2 * t,     saA, saB, kA0, kA1, vA0, vA1);
        iter(2 * t + 1, saB, saA, kB0, kB1, vB0, vB1);
    }

    // epilogue: normalized fp16 partial O/l -> part[half][bh][s][64]; (m,l)
    uint16_t* __restrict__ pd = half ? part1 : part0;
    const float li = 1.f / l_run;
    const int srow = qt * 128 + wq * 32 + lq;
    const size_t rbase = ((size_t)bh * S_LEN + srow) * DOUT;
    #pragma unroll
    for (int dh = 0; dh < 2; ++dh) {
        #pragma unroll
        for (int rq = 0; rq < 4; ++rq) {
            const int d0 = dh * 32 + rq * 8 + L * 4;
            uint2 val;
            val.x = cvt_pkrtz_f16(Oa[dh][rq * 4 + 0] * li, Oa[dh][rq * 4 + 1] * li);
            val.y = cvt_pkrtz_f16(Oa[dh][rq * 4 + 2] * li, Oa[dh][rq * 4 + 3] * li);
            *(uint2*)(pd + rbase + d0) = val;
        }
    }
    if (L == 0) {
        float2 v; v.x = m_run; v.y = l_run;
        ml[((size_t)half << 16) | ((size_t)bh << 11) | (size_t)srow] = v;
    }
}

// ---------------------------------------------------------------------------
// Kernel 5: merge the two KV-half partials -> oc[b][s][h*64+d] bf16.
//   O = (w0*O0n + w1*O1n)/(w0+w1), w_i = l_i * 2^(m_i - max(m0,m1)).
// ---------------------------------------------------------------------------
__global__ __launch_bounds__(256) void merge_o(
    const uint16_t* __restrict__ part0, const uint16_t* __restrict__ part1,
    const float2* __restrict__ ml, uint16_t* __restrict__ oc)
{
    const int g = blockIdx.x * 256 + threadIdx.x;   // 524288 = 65536 rows x 8
    const int row = g >> 3, dp = (g & 7) * 8;
    const int bh = row >> 11, s = row & 2047;

    const float2 ml0 = ml[row];
    const float2 ml1 = ml[65536 + row];
    const float m = fmaxf(ml0.x, ml1.x);
    float w0 = ml0.y * __builtin_amdgcn_exp2f(ml0.x - m);
    float w1 = ml1.y * __builtin_amdgcn_exp2f(ml1.x - m);
    const float inv = 1.f / (w0 + w1);
    w0 *= inv; w1 *= inv;

    const size_t poff = (size_t)row * 64 + dp;
    union { uint4 u; f16x8 v; } a, b;
    a.u = *(const uint4*)(part0 + poff);
    b.u = *(const uint4*)(part1 + poff);
    union { uint32_t w[4]; uint4 u; } r;
    #pragma unroll
    for (int j = 0; j < 4; ++j) {
        const float o0 = w0 * (float)a.v[2 * j]     + w1 * (float)b.v[2 * j];
        const float o1 = w0 * (float)a.v[2 * j + 1] + w1 * (float)b.v[2 * j + 1];
        r.w[j] = cvt_pk_bf16(o0, o1);
    }
    const int bb = bh >> 3, h = bh & 7;
    *(uint4*)(oc + ((size_t)(bb * S_LEN + s) * (NH * DOUT)) + h * DOUT + dp) = r.u;
}

// ---------------------------------------------------------------------------
// Kernel 6: output projection out = o_concat[8192x512] @ wo[512x64], fp32 out.
// ---------------------------------------------------------------------------
__global__ __launch_bounds__(256) void oproj(
    const uint16_t* __restrict__ oc, const uint16_t* __restrict__ woT,
    float* __restrict__ out)
{
    const int mt = blockIdx.x;
    const int tid = threadIdx.x;
    const int l = tid & 63, w = tid >> 6;
    const int g = l >> 4, lm = l & 15;
    const int m0 = mt * 64 + w * 16;
    const f32x4 Z = {0.f, 0.f, 0.f, 0.f};
    f32x4 acc[4] = {Z, Z, Z, Z};
    const uint16_t* __restrict__ arow = oc + (size_t)(m0 + lm) * (NH * DOUT);
    for (int kc = 0; kc < 16; ++kc) {
        const bf16x8 a = *(const bf16x8*)(arow + kc * 32 + g * 8);
        #pragma unroll
        for (int nt = 0; nt < 4; ++nt) {
            const bf16x8 bfr = *(const bf16x8*)(woT + (size_t)(nt * 16 + lm) * (NH * DOUT) + kc * 32 + g * 8);
            acc[nt] = mfma16(a, bfr, acc[nt]);
        }
    }
    #pragma unroll
    for (int nt = 0; nt < 4; ++nt)
        #pragma unroll
        for (int j = 0; j < 4; ++j)
            out[(size_t)(m0 + 4 * g + j) * DOUT + nt * 16 + lm] = acc[nt][j];
}

// ---------------------------------------------------------------------------
extern "C" void kernel_launch(void* const* d_in, const int* in_sizes, int n_in,
                              void* d_out, int out_size, void* d_ws, size_t ws_size,
                              hipStream_t stream) {
    const float* x  = (const float*)d_in[0];
    const float* w  = (const float*)d_in[1];
    const float* wo = (const float*)d_in[2];
    float* out = (float*)d_out;

    char* ws = (char*)d_ws;
    uint16_t* qf    = (uint16_t*)(ws);              // [B*H][S][64] fp16, 8 MB
    uint16_t* kfm   = (uint16_t*)(ws + 8388608);    // fragment-major K, 8 MB
    uint16_t* vfm   = (uint16_t*)(ws + 16777216);   // fragment-major V, 8 MB
    uint16_t* xhi   = (uint16_t*)(ws + 25165824);   // bf16, 8 MB (-> oc)
    uint16_t* xlo   = (uint16_t*)(ws + 33554432);   // bf16, 8 MB (-> part0)
    uint16_t* part1 = (uint16_t*)(ws + 41943040);   // fp16 partial, 8 MB
    float2*   ml    = (float2*)  (ws + 50331648);   // [2][32][2048] f32x2, 1 MB
    uint16_t* whiT  = (uint16_t*)(ws + 51380224);   // [1536][512] bf16
    uint16_t* wloT  = (uint16_t*)(ws + 52953088);
    uint16_t* woT   = (uint16_t*)(ws + 54525952);   // 65536 B
    // aliases: oc over xhi, part0 over xlo (both dead after gemm_qkv;
    // split_x rewrites them every call before gemm_qkv reads them).
    uint16_t* oc    = xhi;
    uint16_t* part0 = xlo;

    hipLaunchKernelGGL(prep_w, dim3(200), dim3(256), 0, stream, w, wo, whiT, wloT, woT);
    hipLaunchKernelGGL(split_x, dim3(2048), dim3(256), 0, stream, x, xhi, xlo);
    hipLaunchKernelGGL(gemm_qkv, dim3(768), dim3(256), 0, stream,
                       xhi, xlo, whiT, wloT, qf, kfm, vfm);
    hipLaunchKernelGGL(attn_fwd, dim3(1024), dim3(256), 0, stream,
                       qf, kfm, vfm, part0, part1, ml);
    hipLaunchKernelGGL(merge_o, dim3(2048), dim3(256), 0, stream,
                       part0, part1, ml, oc);
    hipLaunchKernelGGL(oproj, dim3(128), dim3(256), 0, stream, oc, woT, out);
}

// Round 19
// 114.944 us; speedup vs baseline: 1.0744x; 1.0744x over previous
//
#include <hip/hip_runtime.h>
#include <cstdint>
#include <cstddef>

#define S_LEN 2048
#define DIN   512
#define DOUT  64
#define NB    4
#define NH    8

typedef __attribute__((ext_vector_type(8))) short bf16x8;
typedef __attribute__((ext_vector_type(8))) _Float16 f16x8;
typedef __attribute__((ext_vector_type(4))) float f32x4;
typedef __attribute__((ext_vector_type(16))) float f32x16;

static __device__ __forceinline__ f32x4 mfma16(bf16x8 a, bf16x8 b, f32x4 c) {
    return __builtin_amdgcn_mfma_f32_16x16x32_bf16(a, b, c, 0, 0, 0);
}
static __device__ __forceinline__ f32x16 mfma32h(f16x8 a, f16x8 b, f32x16 c) {
    return __builtin_amdgcn_mfma_f32_32x32x16_f16(a, b, c, 0, 0, 0);
}

static __device__ __forceinline__ uint16_t f2bf(float x) {
    uint32_t u = __builtin_bit_cast(uint32_t, x);
    u += 0x7fffu + ((u >> 16) & 1u);
    return (uint16_t)(u >> 16);
}
static __device__ __forceinline__ float bf2f(uint16_t h) {
    uint32_t u = ((uint32_t)h) << 16;
    return __builtin_bit_cast(float, u);
}
static __device__ __forceinline__ uint32_t cvt_pk_bf16(float lo, float hi) {
    uint32_t r;
    asm("v_cvt_pk_bf16_f32 %0, %1, %2" : "=v"(r) : "v"(lo), "v"(hi));
    return r;
}
static __device__ __forceinline__ uint32_t cvt_pkrtz_f16(float lo, float hi) {
    return __builtin_bit_cast(uint32_t, __builtin_amdgcn_cvt_pkrtz(lo, hi));
}

// ---------------------------------------------------------------------------
// Kernel 1: weight prep via LDS transpose (coalesced both sides).
// ---------------------------------------------------------------------------
__global__ __launch_bounds__(256) void prep_w(
    const float* __restrict__ w, const float* __restrict__ wo,
    uint16_t* __restrict__ whiT, uint16_t* __restrict__ wloT,
    uint16_t* __restrict__ woT)
{
    __shared__ float tile[64][65];
    const int blk = blockIdx.x;
    const int t = threadIdx.x;
    const int tq = t >> 6, tr = t & 63;

    if (blk < 192) {
        const int hp = blk >> 3, i0 = (blk & 7) * 64;
        const int p = hp % 3;
        const float s = (p == 0) ? 0.18033688011112042f : 1.0f; // 0.125*log2(e)
        const float* __restrict__ src = w + (size_t)hp * (DIN * DOUT);
        #pragma unroll
        for (int r = 0; r < 16; ++r) {
            const int ir = r * 4 + tq;
            tile[ir][tr] = src[(size_t)(i0 + ir) * DOUT + tr];
        }
        __syncthreads();
        uint16_t* __restrict__ dh = whiT + (size_t)hp * (DOUT * DIN);
        uint16_t* __restrict__ dl = wloT + (size_t)hp * (DOUT * DIN);
        #pragma unroll
        for (int r = 0; r < 16; ++r) {
            const int o = r * 4 + tq;
            const float v = tile[tr][o] * s;
            const uint16_t hi = f2bf(v);
            dh[(size_t)o * DIN + i0 + tr] = hi;
            dl[(size_t)o * DIN + i0 + tr] = f2bf(v - bf2f(hi));
        }
    } else {
        const int i0 = (blk - 192) * 64;
        #pragma unroll
        for (int r = 0; r < 16; ++r) {
            const int ir = r * 4 + tq;
            tile[ir][tr] = wo[(size_t)(i0 + ir) * DOUT + tr];
        }
        __syncthreads();
        #pragma unroll
        for (int r = 0; r < 16; ++r) {
            const int o = r * 4 + tq;
            woT[(size_t)o * DIN + i0 + tr] = f2bf(tile[tr][o]);
        }
    }
}

// ---------------------------------------------------------------------------
// Kernel 2: split x [8192][512] fp32 -> xhi/xlo bf16 (vectorized, one pass).
// ---------------------------------------------------------------------------
__global__ __launch_bounds__(256) void split_x(
    const float* __restrict__ x, uint16_t* __restrict__ xhi, uint16_t* __restrict__ xlo)
{
    const size_t idx = ((size_t)blockIdx.x * 256 + threadIdx.x) * 8;
    const float4 a = *(const float4*)(x + idx);
    const float4 b = *(const float4*)(x + idx + 4);
    const float xv[8] = {a.x, a.y, a.z, a.w, b.x, b.y, b.z, b.w};
    union { uint16_t u[8]; uint4 v; } H, L;
    #pragma unroll
    for (int j = 0; j < 8; ++j) {
        const uint16_t hi = f2bf(xv[j]);
        H.u[j] = hi;
        L.u[j] = f2bf(xv[j] - bf2f(hi));
    }
    *(uint4*)(xhi + idx) = H.v;
    *(uint4*)(xlo + idx) = L.v;
}

// ---------------------------------------------------------------------------
// Kernel 3: QKV projection GEMM (fused 3-term, reg-staged; proven R15/R17
// body). Outputs: q fp16 [bh][s][64]; K,V fragment-major tiles.
// ---------------------------------------------------------------------------
__global__ __launch_bounds__(256, 2) void gemm_qkv(
    const uint16_t* __restrict__ xhi, const uint16_t* __restrict__ xlo,
    const uint16_t* __restrict__ whiT, const uint16_t* __restrict__ wloT,
    uint16_t* __restrict__ qf, uint16_t* __restrict__ kfm,
    uint16_t* __restrict__ vfm)
{
    __shared__ __align__(16) uint16_t lds[4 * 128 * 64];   // 64 KB: ah|al|bh|bl

    const int bid = blockIdx.x;
    const int xcd = bid & 7, wi = bid >> 3;
    const int mt = xcd * 8 + wi / 12, nt = wi % 12;
    const int m0 = mt * 128, n0 = nt * 128;
    const int tid = threadIdx.x;
    const int l = tid & 63, w = tid >> 6;
    const int g = l >> 4, lm = l & 15;
    const int wm = w >> 1, wn = w & 1;

    const f32x4 Z = {0.f, 0.f, 0.f, 0.f};
    f32x4 acc[4][4];
    #pragma unroll
    for (int a = 0; a < 4; ++a)
        #pragma unroll
        for (int b = 0; b < 4; ++b) acc[a][b] = Z;

    int srow[4], scol[4];
    #pragma unroll
    for (int i = 0; i < 4; ++i) {
        const int c = i * 256 + tid;
        srow[i] = c >> 3;
        scol[i] = ((c & 7) * 8) ^ ((srow[i] & 7) << 3);
    }

    for (int kt = 0; kt < 8; ++kt) {
        const int k0 = kt * 64;
        uint4 stg[16];
        #pragma unroll
        for (int i = 0; i < 4; ++i) {
            const size_t aoff = (size_t)(m0 + srow[i]) * DIN + k0 + scol[i];
            const size_t boff = (size_t)(n0 + srow[i]) * DIN + k0 + scol[i];
            stg[i * 4 + 0] = *(const uint4*)(xhi  + aoff);
            stg[i * 4 + 1] = *(const uint4*)(xlo  + aoff);
            stg[i * 4 + 2] = *(const uint4*)(whiT + boff);
            stg[i * 4 + 3] = *(const uint4*)(wloT + boff);
        }
        #pragma unroll
        for (int i = 0; i < 4; ++i) {
            const int c8 = (i * 256 + tid) * 8;
            *(uint4*)&lds[c8]                 = stg[i * 4 + 0];
            *(uint4*)&lds[128 * 64 + c8]      = stg[i * 4 + 1];
            *(uint4*)&lds[2 * 128 * 64 + c8]  = stg[i * 4 + 2];
            *(uint4*)&lds[3 * 128 * 64 + c8]  = stg[i * 4 + 3];
        }
        __syncthreads();

        bf16x8 ah[4][2], al[4][2];
        #pragma unroll
        for (int mi = 0; mi < 4; ++mi) {
            const int r = wm * 64 + mi * 16 + lm;
            const int rb = r * 128;
            #pragma unroll
            for (int kk = 0; kk < 2; ++kk) {
                const int cb = (kk * 64 + g * 16) ^ ((r & 7) << 4);
                ah[mi][kk] = *(const bf16x8*)((const char*)lds + rb + cb);
                al[mi][kk] = *(const bf16x8*)((const char*)lds + 16384 + rb + cb);
            }
        }
        #pragma unroll
        for (int ni = 0; ni < 4; ++ni) {
            const int r = wn * 64 + ni * 16 + lm;
            const int rb = r * 128;
            bf16x8 bh[2], bl[2];
            #pragma unroll
            for (int kk = 0; kk < 2; ++kk) {
                const int cb = (kk * 64 + g * 16) ^ ((r & 7) << 4);
                bh[kk] = *(const bf16x8*)((const char*)lds + 32768 + rb + cb);
                bl[kk] = *(const bf16x8*)((const char*)lds + 49152 + rb + cb);
            }
            #pragma unroll
            for (int mi = 0; mi < 4; ++mi) {
                acc[mi][ni] = mfma16(ah[mi][0], bh[0], acc[mi][ni]);
                acc[mi][ni] = mfma16(ah[mi][1], bh[1], acc[mi][ni]);
                acc[mi][ni] = mfma16(ah[mi][0], bl[0], acc[mi][ni]);
                acc[mi][ni] = mfma16(ah[mi][1], bl[1], acc[mi][ni]);
                acc[mi][ni] = mfma16(al[mi][0], bh[0], acc[mi][ni]);
                acc[mi][ni] = mfma16(al[mi][1], bh[1], acc[mi][ni]);
            }
        }
        __syncthreads();
    }

    #pragma unroll
    for (int ni = 0; ni < 4; ++ni) {
        const int n = n0 + wn * 64 + ni * 16 + lm;
        const int hp = n >> 6, o = n & 63;
        const int h = hp / 3, p = hp - h * 3;
        if (p == 0) {
            #pragma unroll
            for (int mi = 0; mi < 4; ++mi) {
                #pragma unroll
                for (int j = 0; j < 4; ++j) {
                    const int m = m0 + wm * 64 + mi * 16 + 4 * g + j;
                    const int b = m >> 11, s = m & 2047;
                    const size_t idx = ((size_t)(b * NH + h) * S_LEN + s) * DOUT + o;
                    const _Float16 hv = (_Float16)acc[mi][ni][j];  // RNE
                    qf[idx] = __builtin_bit_cast(uint16_t, hv);
                }
            }
        } else if (p == 1) {
            #pragma unroll
            for (int mi = 0; mi < 4; ++mi) {
                const int m = m0 + wm * 64 + mi * 16 + 4 * g;
                const int b = m >> 11, s = m & 2047;
                const int tile = s >> 6, sr = s & 63;
                const int gam = ((sr >> 5) * 4 + (o >> 4)) * 64 + ((o >> 3) & 1) * 32 + (sr & 31);
                uint16_t* __restrict__ dst =
                    kfm + ((size_t)((b * NH + h) * 32 + tile)) * 4096 + gam * 8 + (o & 7);
                #pragma unroll
                for (int j = 0; j < 4; ++j) {
                    const _Float16 hv = (_Float16)acc[mi][ni][j];
                    dst[j * 8] = __builtin_bit_cast(uint16_t, hv);  // granule+1 = +8 elem
                }
            }
        } else {
            #pragma unroll
            for (int mi = 0; mi < 4; ++mi) {
                const int m = m0 + wm * 64 + mi * 16 + 4 * g;
                const int b = m >> 11, s = m & 2047;
                const int tile = s >> 6, sc = s & 63;
                const int gam = ((o >> 5) * 4 + (sc >> 4)) * 64 + ((sc >> 3) & 1) * 32 + (o & 31);
                union { _Float16 h[4]; uint2 u; } pk;
                pk.h[0] = (_Float16)acc[mi][ni][0];
                pk.h[1] = (_Float16)acc[mi][ni][1];
                pk.h[2] = (_Float16)acc[mi][ni][2];
                pk.h[3] = (_Float16)acc[mi][ni][3];
                *(uint2*)(vfm + ((size_t)((b * NH + h) * 32 + tile)) * 4096
                              + gam * 8 + (sc & 7)) = pk.u;
            }
        }
    }
}

// ---------------------------------------------------------------------------
// Kernel 4: flash attention, T19 sched_group_barrier interleave.
//   Single-pass (grid 512, R17 structure). Compute body is ONE scheduling
//   region (branchless rescale, no fences inside); the SGB ladder forces
//   {1 MFMA, k VALU} emission so softmax(kt) VALU fills QK(kt+1)/PV MFMA
//   latency (waves issue in order — this is the measured serialization).
// ---------------------------------------------------------------------------
__global__ __launch_bounds__(256, 2) void attn_fwd(
    const uint16_t* __restrict__ qf, const uint16_t* __restrict__ kfm,
    const uint16_t* __restrict__ vfm, uint16_t* __restrict__ oc)
{
    __shared__ __align__(16) char smem[32768];
    // kbuf0 @0, kbuf1 @8192, vbuf0 @16384, vbuf1 @24576
    char* __restrict__ vbufs = smem + 16384;

    const int bid = blockIdx.x;
    const int qt = (bid >> 3) & 15, bh = (bid & 7) + 8 * (bid >> 7);
    const int tid = threadIdx.x;
    const int l = tid & 63, wq = tid >> 6;
    const int L = l >> 5, lq = l & 31;
    const size_t base = (size_t)bh * (S_LEN * DOUT);

    const uint16_t* __restrict__ ktb = kfm + (size_t)bh * 131072;
    const uint16_t* __restrict__ vtb = vfm + (size_t)bh * 131072;
    const uint32_t t16 = (uint32_t)tid * 16;

    const int qrow = qt * 128 + wq * 32 + lq;
    const uint16_t* qp = qf + base + (size_t)qrow * DOUT;
    f16x8 qv[4];
    #pragma unroll
    for (int dsub = 0; dsub < 4; ++dsub)
        qv[dsub] = *(const f16x8*)(qp + dsub * 16 + L * 8);

    f32x16 Zv;
    #pragma unroll
    for (int r = 0; r < 16; ++r) Zv[r] = 0.f;
    f32x16 Oa[2] = {Zv, Zv};
    float m_run = -120.f, l_run = 0.f;   // finite init (branchless rescale)

    // named staging regs (2 sets x {K lo/hi half, V lo/hi half})
    uint4 kA0, kA1, vA0, vA1, kB0, kB1, vB0, vB1;

    auto qk_step = [&](const char* kb2, f32x16* dst) {
        #pragma unroll
        for (int ks = 0; ks < 2; ++ks) {
            f32x16 s = Zv;
            #pragma unroll
            for (int dsub = 0; dsub < 4; ++dsub) {
                const uint32_t off = (uint32_t)(((ks * 4 + dsub) << 10) + (l << 4));
                const f16x8 kfr = *(const f16x8*)(kb2 + off);
                s = mfma32h(kfr, qv[dsub], s);
            }
            dst[ks] = s;
        }
    };

    // prologue: tiles 0,1 loaded+committed; tiles 2,3 issued (in flight)
    kA0 = *(const uint4*)(ktb + (size_t)tid * 8);
    kA1 = *(const uint4*)(ktb + 2048 + (size_t)tid * 8);
    vA0 = *(const uint4*)(vtb + (size_t)tid * 8);
    vA1 = *(const uint4*)(vtb + 2048 + (size_t)tid * 8);
    kB0 = *(const uint4*)(ktb + 4096 + (size_t)tid * 8);
    kB1 = *(const uint4*)(ktb + 6144 + (size_t)tid * 8);
    vB0 = *(const uint4*)(vtb + 4096 + (size_t)tid * 8);
    vB1 = *(const uint4*)(vtb + 6144 + (size_t)tid * 8);
    *(uint4*)(smem + t16)          = kA0;
    *(uint4*)(smem + 4096 + t16)   = kA1;
    *(uint4*)(vbufs + t16)         = vA0;
    *(uint4*)(vbufs + 4096 + t16)  = vA1;
    *(uint4*)(smem + 8192 + t16)   = kB0;
    *(uint4*)(smem + 12288 + t16)  = kB1;
    *(uint4*)(vbufs + 8192 + t16)  = vB0;
    *(uint4*)(vbufs + 12288 + t16) = vB1;
    {
        const size_t o2 = (size_t)2 * 4096 + tid * 8, o3 = (size_t)3 * 4096 + tid * 8;
        kA0 = *(const uint4*)(ktb + o2); kA1 = *(const uint4*)(ktb + o2 + 2048);
        vA0 = *(const uint4*)(vtb + o2); vA1 = *(const uint4*)(vtb + o2 + 2048);
        kB0 = *(const uint4*)(ktb + o3); kB1 = *(const uint4*)(ktb + o3 + 2048);
        vB0 = *(const uint4*)(vtb + o3); vB1 = *(const uint4*)(vtb + o3 + 2048);
    }
    asm volatile("s_waitcnt lgkmcnt(0)" ::: "memory");
    __builtin_amdgcn_s_barrier();
    __builtin_amdgcn_sched_barrier(0);

    f32x16 saA[2], saB[2];
    qk_step(smem, saA);        // QK(0) from kbuf0

    auto iter = [&](int kt, f32x16* sa, f32x16* sb,
                    uint4& k0, uint4& k1, uint4& v0, uint4& v1) {
        // ======== compute region (one sched region; ladder at end) ========
        // QK(kt+1) -> sb (24 MFMAs incl PV below; 16 here)
        qk_step(smem + ((kt + 1) & 1) * 8192, sb);

        // PV operand reads (8 ds_read_b128)
        const char* __restrict__ vb = vbufs + (kt & 1) * 8192;
        const uint32_t vo = (uint32_t)(l << 4);
        const f16x8 pv0 = *(const f16x8*)(vb + (0u << 10) + vo);
        const f16x8 pv1 = *(const f16x8*)(vb + (1u << 10) + vo);
        const f16x8 pv2 = *(const f16x8*)(vb + (2u << 10) + vo);
        const f16x8 pv3 = *(const f16x8*)(vb + (3u << 10) + vo);
        const f16x8 pv4 = *(const f16x8*)(vb + (4u << 10) + vo);
        const f16x8 pv5 = *(const f16x8*)(vb + (5u << 10) + vo);
        const f16x8 pv6 = *(const f16x8*)(vb + (6u << 10) + vo);
        const f16x8 pv7 = *(const f16x8*)(vb + (7u << 10) + vo);

        // softmax(kt), branchless always-rescale (no region-splitting branch)
        float mx[16];
        #pragma unroll
        for (int r = 0; r < 16; ++r) mx[r] = fmaxf(sa[0][r], sa[1][r]);
        #pragma unroll
        for (int st = 8; st >= 1; st >>= 1)
            #pragma unroll
            for (int r = 0; r < st; ++r) mx[r] = fmaxf(mx[r], mx[r + st]);
        float pmax = mx[0];
        pmax = fmaxf(pmax, __shfl_xor(pmax, 32));

        const float m_new = fmaxf(m_run, pmax);
        const float alpha = __builtin_amdgcn_exp2f(m_run - m_new);
        m_run = m_new;
        #pragma unroll
        for (int r = 0; r < 16; ++r) { Oa[0][r] *= alpha; Oa[1][r] *= alpha; }
        l_run *= alpha;

        #pragma unroll
        for (int ks = 0; ks < 2; ++ks)
            #pragma unroll
            for (int r = 0; r < 16; ++r)
                sa[ks][r] = __builtin_amdgcn_exp2f(sa[ks][r] - m_run);

        float sm[16];
        #pragma unroll
        for (int r = 0; r < 16; ++r) sm[r] = sa[0][r] + sa[1][r];
        #pragma unroll
        for (int st = 8; st >= 1; st >>= 1)
            #pragma unroll
            for (int r = 0; r < st; ++r) sm[r] += sm[r + st];
        float lsum = sm[0];
        lsum += __shfl_xor(lsum, 32);
        l_run += lsum;

        // pack P (fp16) into PV B-fragments; permlane VDST = lo pack
        f16x8 pfrag[4];
        #pragma unroll
        for (int ks = 0; ks < 2; ++ks) {
            uint32_t a0 = cvt_pkrtz_f16(sa[ks][0], sa[ks][1]);
            uint32_t a1 = cvt_pkrtz_f16(sa[ks][2], sa[ks][3]);
            uint32_t a2 = cvt_pkrtz_f16(sa[ks][4], sa[ks][5]);
            uint32_t a3 = cvt_pkrtz_f16(sa[ks][6], sa[ks][7]);
            asm volatile("v_permlane32_swap_b32 %0, %1" : "+v"(a0), "+v"(a2));
            asm volatile("v_permlane32_swap_b32 %0, %1" : "+v"(a1), "+v"(a3));
            union { uint32_t w[4]; f16x8 v; } u;
            u.w[0] = a0; u.w[1] = a1; u.w[2] = a2; u.w[3] = a3;
            pfrag[2 * ks] = u.v;
            uint32_t b0 = cvt_pkrtz_f16(sa[ks][8],  sa[ks][9]);
            uint32_t b1 = cvt_pkrtz_f16(sa[ks][10], sa[ks][11]);
            uint32_t b2 = cvt_pkrtz_f16(sa[ks][12], sa[ks][13]);
            uint32_t b3 = cvt_pkrtz_f16(sa[ks][14], sa[ks][15]);
            asm volatile("v_permlane32_swap_b32 %0, %1" : "+v"(b0), "+v"(b2));
            asm volatile("v_permlane32_swap_b32 %0, %1" : "+v"(b1), "+v"(b3));
            union { uint32_t w[4]; f16x8 v; } u2;
            u2.w[0] = b0; u2.w[1] = b1; u2.w[2] = b2; u2.w[3] = b3;
            pfrag[2 * ks + 1] = u2.v;
        }

        // PV(kt) (8 MFMAs)
        Oa[0] = mfma32h(pv0, pfrag[0], Oa[0]);
        Oa[0] = mfma32h(pv1, pfrag[1], Oa[0]);
        Oa[0] = mfma32h(pv2, pfrag[2], Oa[0]);
        Oa[0] = mfma32h(pv3, pfrag[3], Oa[0]);
        Oa[1] = mfma32h(pv4, pfrag[0], Oa[1]);
        Oa[1] = mfma32h(pv5, pfrag[1], Oa[1]);
        Oa[1] = mfma32h(pv6, pfrag[2], Oa[1]);
        Oa[1] = mfma32h(pv7, pfrag[3], Oa[1]);

        // ---- T19 ladder: ds_reads first, then {1 MFMA, k VALU} pairs ----
        __builtin_amdgcn_sched_group_barrier(0x100, 16, 0);   // DS_READ x16
        #pragma unroll
        for (int i = 0; i < 16; ++i) {                         // QK ⊗ softmax
            __builtin_amdgcn_sched_group_barrier(0x008, 1, 0); // 1 MFMA
            __builtin_amdgcn_sched_group_barrier(0x002, 8, 0); // 8 VALU
        }
        #pragma unroll
        for (int i = 0; i < 8; ++i) {                          // PV ⊗ packs
            __builtin_amdgcn_sched_group_barrier(0x008, 1, 0);
            __builtin_amdgcn_sched_group_barrier(0x002, 6, 0);
        }
        // ======== end compute region ========

        // staging: commit tile kt+2, issue kt+4
        __builtin_amdgcn_sched_barrier(0);
        __builtin_amdgcn_s_barrier();
        {
            char* __restrict__ kb = smem + (kt & 1) * 8192;
            char* __restrict__ vbw = vbufs + (kt & 1) * 8192;
            *(uint4*)(kb + t16)         = k0;
            *(uint4*)(kb + 4096 + t16)  = k1;
            *(uint4*)(vbw + t16)        = v0;
            *(uint4*)(vbw + 4096 + t16) = v1;
            const int tk = (kt + 4 < 32) ? kt + 4 : 0;
            const size_t toff = (size_t)tk * 4096 + tid * 8;
            k0 = *(const uint4*)(ktb + toff);
            k1 = *(const uint4*)(ktb + toff + 2048);
            v0 = *(const uint4*)(vtb + toff);
            v1 = *(const uint4*)(vtb + toff + 2048);
        }
        asm volatile("s_waitcnt lgkmcnt(0)" ::: "memory");
        __builtin_amdgcn_sched_barrier(0);
        __builtin_amdgcn_s_barrier();
    };

    for (int t = 0; t < 16; ++t) {
        iter(2 * t,     saA, saB, kA0, kA1, vA0, vA1);
        iter(2 * t + 1, saB, saA, kB0, kB1, vB0, vB1);
    }

    // epilogue: lane-local normalize; O^T -> oc[b][s][h*64+d] bf16, 8B packed
    const int b = bh >> 3, hh = bh & 7;
    const float li = 1.f / l_run;
    const int srow = qt * 128 + wq * 32 + lq;
    const size_t rbase = ((size_t)b * S_LEN + srow) * (NH * DOUT) + hh * DOUT;
    #pragma unroll
    for (int dh = 0; dh < 2; ++dh) {
        #pragma unroll
        for (int rq = 0; rq < 4; ++rq) {
            const int d0 = dh * 32 + rq * 8 + L * 4;
            uint2 val;
            val.x = cvt_pk_bf16(Oa[dh][rq * 4 + 0] * li, Oa[dh][rq * 4 + 1] * li);
            val.y = cvt_pk_bf16(Oa[dh][rq * 4 + 2] * li, Oa[dh][rq * 4 + 3] * li);
            *(uint2*)(oc + rbase + d0) = val;
        }
    }
}

// ---------------------------------------------------------------------------
// Kernel 5: output projection out = o_concat[8192x512] @ wo[512x64], fp32 out.
// ---------------------------------------------------------------------------
__global__ __launch_bounds__(256) void oproj(
    const uint16_t* __restrict__ oc, const uint16_t* __restrict__ woT,
    float* __restrict__ out)
{
    const int mt = blockIdx.x;
    const int tid = threadIdx.x;
    const int l = tid & 63, w = tid >> 6;
    const int g = l >> 4, lm = l & 15;
    const int m0 = mt * 64 + w * 16;
    const f32x4 Z = {0.f, 0.f, 0.f, 0.f};
    f32x4 acc[4] = {Z, Z, Z, Z};
    const uint16_t* __restrict__ arow = oc + (size_t)(m0 + lm) * (NH * DOUT);
    for (int kc = 0; kc < 16; ++kc) {
        const bf16x8 a = *(const bf16x8*)(arow + kc * 32 + g * 8);
        #pragma unroll
        for (int nt = 0; nt < 4; ++nt) {
            const bf16x8 bfr = *(const bf16x8*)(woT + (size_t)(nt * 16 + lm) * (NH * DOUT) + kc * 32 + g * 8);
            acc[nt] = mfma16(a, bfr, acc[nt]);
        }
    }
    #pragma unroll
    for (int nt = 0; nt < 4; ++nt)
        #pragma unroll
        for (int j = 0; j < 4; ++j)
            out[(size_t)(m0 + 4 * g + j) * DOUT + nt * 16 + lm] = acc[nt][j];
}

// ---------------------------------------------------------------------------
extern "C" void kernel_launch(void* const* d_in, const int* in_sizes, int n_in,
                              void* d_out, int out_size, void* d_ws, size_t ws_size,
                              hipStream_t stream) {
    const float* x  = (const float*)d_in[0];
    const float* w  = (const float*)d_in[1];
    const float* wo = (const float*)d_in[2];
    float* out = (float*)d_out;

    char* ws = (char*)d_ws;
    uint16_t* qf   = (uint16_t*)(ws);              // [B*H][S][64] fp16, 8 MB
    uint16_t* kfm  = (uint16_t*)(ws + 8388608);    // fragment-major K, 8 MB
    uint16_t* vfm  = (uint16_t*)(ws + 16777216);   // fragment-major V, 8 MB
    uint16_t* xhi  = (uint16_t*)(ws + 25165824);   // bf16, 8 MB (-> oc)
    uint16_t* xlo  = (uint16_t*)(ws + 33554432);   // bf16, 8 MB
    uint16_t* whiT = (uint16_t*)(ws + 41943040);   // [1536][512] bf16
    uint16_t* wloT = (uint16_t*)(ws + 43515904);
    uint16_t* woT  = (uint16_t*)(ws + 45088768);   // 65536 B
    // oc aliases xhi (dead after gemm_qkv; split_x rewrites it every call).
    uint16_t* oc   = xhi;

    hipLaunchKernelGGL(prep_w, dim3(200), dim3(256), 0, stream, w, wo, whiT, wloT, woT);
    hipLaunchKernelGGL(split_x, dim3(2048), dim3(256), 0, stream, x, xhi, xlo);
    hipLaunchKernelGGL(gemm_qkv, dim3(768), dim3(256), 0, stream,
                       xhi, xlo, whiT, wloT, qf, kfm, vfm);
    hipLaunchKernelGGL(attn_fwd, dim3(512), dim3(256), 0, stream,
                       qf, kfm, vfm, oc);
    hipLaunchKernelGGL(oproj, dim3(128), dim3(256), 0, stream, oc, woT, out);
}